// Round 11
// baseline (157.150 us; speedup 1.0000x reference)
//
#include <hip/hip_runtime.h>

#define NN 8192
#define DIN 128
#define DH 64
#define DOUT 16
#define KS 16

typedef _Float16 half8 __attribute__((ext_vector_type(8)));
typedef float f32x4 __attribute__((ext_vector_type(4)));

// workspace layout (bytes); ws ~1GB
#define OFF_PART  0u         // part[242]: 0..239 X partial max, 240 Wi, 241 Wo
#define OFF_PART2 2048u      // part2[512]: per-block max |h_int|
#define OFF_YB    65536u     // f16 [1024 kgrp][64 n][8 k7] (1 MB) Y ints |Y|<=384
#define OFF_RT    1114112u   // f16 [16][8192] (256 KB) R^T ints, k pi-permuted
#define OFF_HF    1376256u   // f32 [8192][64] (2 MB) h as RAW INTEGERS
#define OFF_BITS  3473408u   // u8  [8192][1024] (8 MB) A>0 bitmask, pi-permuted
#define OFF_P1    11862016u  // f32 [16][8192][64] (32 MB)

// pi-permutation within each 256-element group (float4+ballot packing order):
// stored position p <-> element e = 4*(p&63) + (p>>6). Applied to bits, Yb, RT.
__device__ __forceinline__ int permk(int k) {
  int e = k & 255;
  return (k & ~255) | (((e & 3) << 6) | (e >> 2));
}

__device__ __forceinline__ float guard(float s) { return (s == 0.0f) ? 1.0f : s; }

__device__ __forceinline__ half8 expand8(unsigned bb) {  // 8 bits -> 8 f16 {0,1}
  uint4 w;
  w.x = ((bb & 1u)  ? 0x3C00u : 0u) | ((bb & 2u)   ? 0x3C000000u : 0u);
  w.y = ((bb & 4u)  ? 0x3C00u : 0u) | ((bb & 8u)   ? 0x3C000000u : 0u);
  w.z = ((bb & 16u) ? 0x3C00u : 0u) | ((bb & 32u)  ? 0x3C000000u : 0u);
  w.w = ((bb & 64u) ? 0x3C00u : 0u) | ((bb & 128u) ? 0x3C000000u : 0u);
  return __builtin_bit_cast(half8, w);
}

// ---- K0: binarize A (float4 + 4x ballot, pi order) + abs-max partials -------
__global__ __launch_bounds__(256) void k_f0(const float* __restrict__ A,
                                            const float* __restrict__ X,
                                            const float* __restrict__ Wi,
                                            const float* __restrict__ Wo,
                                            unsigned char* __restrict__ bits,
                                            unsigned* __restrict__ part) {
  __shared__ float red0[256];
  const int t = threadIdx.x, bid = blockIdx.x;
  const int lane = t & 63, warp = t >> 6;
  for (int c = 0; c < 8; ++c) {
    const size_t wbase = (((size_t)bid * 4 + warp) * 8 + c) * 4096;
    const float4* ap = (const float4*)(A + wbase) + lane;
    unsigned char* bp = bits + (wbase >> 3);
#pragma unroll
    for (int g = 0; g < 16; ++g) {                 // 256 floats per group
      float4 v = ap[g * 64];
      unsigned long long m0 = __ballot(v.x > 0.0f);
      unsigned long long m1 = __ballot(v.y > 0.0f);
      unsigned long long m2 = __ballot(v.z > 0.0f);
      unsigned long long m3 = __ballot(v.w > 0.0f);
      unsigned long long lo = (lane & 1) ? m1 : m0;
      unsigned long long hi = (lane & 1) ? m3 : m2;
      unsigned long long word = (lane & 2) ? hi : lo;
      if (lane < 4) *(unsigned long long*)(bp + g * 32 + lane * 8) = word;
    }
  }
  float m = 0.0f;
  if (bid < 240) {
    for (int i = bid * 256 + t; i < NN * DIN; i += 240 * 256) m = fmaxf(m, fabsf(X[i]));
  } else if (bid == 240) {
    for (int i = t; i < DIN * DH; i += 256) m = fmaxf(m, fabsf(Wi[i]));
  } else if (bid == 241) {
    for (int i = t; i < DH * DOUT; i += 256) m = fmaxf(m, fabsf(Wo[i]));
  }
  if (bid < 242) {
    red0[t] = m; __syncthreads();
    for (int s = 128; s > 0; s >>= 1) {
      if (t < s) red0[t] = fmaxf(red0[t], red0[t + s]);
      __syncthreads();
    }
    if (t == 0) part[bid] = __float_as_uint(red0[0]);
  }
}

// ---- K1: Yb[kp>>3][n][kp&7] = (Xq @ Wiq)  exact ints ------------------------
__global__ __launch_bounds__(256) void k_f1(const float* __restrict__ X,
                                            const float* __restrict__ Wi,
                                            const unsigned* __restrict__ part,
                                            _Float16* __restrict__ Yb) {
  __shared__ float Xs[16][129];
  __shared__ float Ws[DIN][DH];
  __shared__ float red1[256];
  const int t = threadIdx.x, bid = blockIdx.x;
  red1[t] = (t < 240) ? __uint_as_float(part[t]) : 0.0f;
  __syncthreads();
  for (int s = 128; s > 0; s >>= 1) {
    if (t < s) red1[t] = fmaxf(red1[t], red1[t + s]);
    __syncthreads();
  }
  const float sx = guard(red1[0] / 3.0f);               // qmax=3
  const float swi = guard(__uint_as_float(part[240]));  // qmax=1
  const int k0 = bid * 16;
  for (int i = t; i < 16 * DIN; i += 256) {
    int r = i >> 7, c = i & 127;
    float q = rintf(X[(size_t)(k0 + r) * DIN + c] / sx);
    Xs[r][c] = fminf(fmaxf(q, -3.0f), 3.0f);
  }
  for (int i = t; i < DIN * DH; i += 256) {
    float q = rintf(Wi[i] / swi);
    Ws[i >> 6][i & 63] = fminf(fmaxf(q, -1.0f), 1.0f);
  }
  __syncthreads();
#pragma unroll
  for (int rg = 0; rg < 2; ++rg) {
    const int r = rg * 8 + (t & 7), j = (t >> 3) * 2;
    float a0 = 0.0f, a1 = 0.0f;
    for (int n = 0; n < DIN; ++n) {
      float xv = Xs[r][n];
      a0 = fmaf(xv, Ws[n][j], a0);
      a1 = fmaf(xv, Ws[n][j + 1], a1);
    }
    const int kp = permk(k0 + r);
    const size_t base = (size_t)(kp >> 3) * 512 + (size_t)j * 8 + (kp & 7);
    Yb[base]     = (_Float16)a0;    // exact integers in f16
    Yb[base + 8] = (_Float16)a1;
  }
}

// ---- K2: h_int = Aq @ Y. Bits->regs, Yb direct from L2 (no LDS, no barriers).
// BM=256 (4 waves x 64 rows), full N=64, 16 splits of 512 k.
__global__ __launch_bounds__(256) void k_f2(const unsigned char* __restrict__ bits,
                                            const _Float16* __restrict__ Yb,
                                            float* __restrict__ P1) {
  const int t = threadIdx.x, bid = blockIdx.x;
  const int lane = t & 63, warp = t >> 6;
  const int l15 = lane & 15, lq = lane >> 4;
  const int rowblk = bid >> 4, split = bid & 15;
  const int row0 = rowblk * 256 + warp * 64;
  f32x4 acc[4][4] = {};
  const unsigned char* b0 = bits + (size_t)(row0 + l15) * 1024 + split * 64;
#pragma unroll
  for (int it = 0; it < 8; ++it) {
    uint2 w[4];
#pragma unroll
    for (int rt = 0; rt < 4; ++rt)
      w[rt] = *(const uint2*)(b0 + (size_t)rt * 16384 + it * 8);
#pragma unroll
    for (int kk = 0; kk < 2; ++kk) {
      const _Float16* yb = Yb + (size_t)(split * 64 + it * 8 + kk * 4 + lq) * 512 + (size_t)l15 * 8;
      half8 bf[4];
#pragma unroll
      for (int nt = 0; nt < 4; ++nt) bf[nt] = *(const half8*)(yb + nt * 128);
#pragma unroll
      for (int rt = 0; rt < 4; ++rt) {
        half8 af = expand8(((kk ? w[rt].y : w[rt].x) >> (lq * 8)) & 0xffu);
#pragma unroll
        for (int nt = 0; nt < 4; ++nt)
          acc[rt][nt] = __builtin_amdgcn_mfma_f32_16x16x32_f16(af, bf[nt], acc[rt][nt], 0, 0, 0);
      }
    }
  }
  const int r4 = lq * 4;
#pragma unroll
  for (int rt = 0; rt < 4; ++rt)
#pragma unroll
    for (int nt = 0; nt < 4; ++nt)
#pragma unroll
      for (int i = 0; i < 4; ++i)
        P1[((size_t)split * NN + row0 + rt * 16 + r4 + i) * DH + nt * 16 + l15] = acc[rt][nt][i];
}

// ---- K3: reduce splits -> h_int (raw ints, sxw cancels later); block max ----
__global__ __launch_bounds__(256) void k_f3(const float* __restrict__ P1,
                                            float* __restrict__ hf,
                                            unsigned* __restrict__ part2) {
  __shared__ float red3[256];
  const int t = threadIdx.x, bid = blockIdx.x;
  const int idx = bid * 256 + t;                   // float4 index, exact cover
  const float4* p = (const float4*)P1;
  float4 s = {0, 0, 0, 0};
#pragma unroll
  for (int sp = 0; sp < KS; ++sp) {
    float4 v = p[(size_t)sp * (NN * DH / 4) + idx];  // exact integer adds
    s.x += v.x; s.y += v.y; s.z += v.z; s.w += v.w;
  }
  ((float4*)hf)[idx] = s;
  float m = fmaxf(fmaxf(fabsf(s.x), fabsf(s.y)), fmaxf(fabsf(s.z), fabsf(s.w)));
  red3[t] = m; __syncthreads();
  for (int st = 128; st > 0; st >>= 1) {
    if (t < st) red3[t] = fmaxf(red3[t], red3[t + st]);
    __syncthreads();
  }
  if (t == 0) part2[bid] = __float_as_uint(red3[0]);   // plain store, no atomics
}

// ---- K4: R^T ints: hq = clip(round(h_int/(maxint/3))) (sxw cancels) ---------
__global__ __launch_bounds__(256) void k_f4(const float* __restrict__ hf,
                                            const float* __restrict__ Wo,
                                            const unsigned* __restrict__ part,
                                            const unsigned* __restrict__ part2,
                                            _Float16* __restrict__ RT) {
  __shared__ float WoS[DH][DOUT];
  __shared__ float red4[256];
  const int t = threadIdx.x, bid = blockIdx.x;
  red4[t] = fmaxf(__uint_as_float(part2[t]), __uint_as_float(part2[t + 256]));
  __syncthreads();
  for (int s = 128; s > 0; s >>= 1) {
    if (t < s) red4[t] = fmaxf(red4[t], red4[t + s]);
    __syncthreads();
  }
  const float shi = guard(red4[0] / 3.0f);
  const float swo = guard(__uint_as_float(part[241]));
  for (int i = t; i < DH * DOUT; i += 256) {
    float q = rintf(Wo[i] / swo);
    WoS[i >> 4][i & 15] = fminf(fmaxf(q, -1.0f), 1.0f);
  }
  __syncthreads();
  const int i = bid * 16 + (t & 15), j = t >> 4;
  const float4* hp = (const float4*)(hf + (size_t)i * DH);
  float acc = 0.0f;
#pragma unroll 4
  for (int nb = 0; nb < 16; ++nb) {
    float4 h4 = hp[nb];
    float q;
    q = fminf(fmaxf(rintf(h4.x / shi), -3.0f), 3.0f); acc = fmaf(q, WoS[nb * 4 + 0][j], acc);
    q = fminf(fmaxf(rintf(h4.y / shi), -3.0f), 3.0f); acc = fmaf(q, WoS[nb * 4 + 1][j], acc);
    q = fminf(fmaxf(rintf(h4.z / shi), -3.0f), 3.0f); acc = fmaf(q, WoS[nb * 4 + 2][j], acc);
    q = fminf(fmaxf(rintf(h4.w / shi), -3.0f), 3.0f); acc = fmaf(q, WoS[nb * 4 + 3][j], acc);
  }
  RT[(size_t)j * NN + permk(i)] = (_Float16)acc;     // |R_int| <= 192, exact
}

// ---- K5: out = shF*swo * (Aq @ R_int), full K in-block ----------------------
__global__ __launch_bounds__(256) void k_f5(const unsigned char* __restrict__ bits,
                                            const _Float16* __restrict__ RT,
                                            const unsigned* __restrict__ part,
                                            const unsigned* __restrict__ part2,
                                            float* __restrict__ out) {
  __shared__ float redP[256];
  __shared__ float red2s[3][16][16];
  const int t = threadIdx.x, bid = blockIdx.x;
  redP[t] = (t < 240) ? __uint_as_float(part[t]) : 0.0f;
  __syncthreads();
  for (int s = 128; s > 0; s >>= 1) {
    if (t < s) redP[t] = fmaxf(redP[t], redP[t + s]);
    __syncthreads();
  }
  const float sxraw = redP[0];
  __syncthreads();                                  // protect redP before reuse
  redP[t] = fmaxf(__uint_as_float(part2[t]), __uint_as_float(part2[t + 256]));
  __syncthreads();
  for (int s = 128; s > 0; s >>= 1) {
    if (t < s) redP[t] = fmaxf(redP[t], redP[t + s]);
    __syncthreads();
  }
  const float maxint = redP[0];
  const float swi = guard(__uint_as_float(part[240]));
  const float swo = guard(__uint_as_float(part[241]));
  const float sx = guard(sxraw / 3.0f);
  const float shF = (maxint == 0.0f) ? 1.0f : (sx * swi) * (maxint / 3.0f);
  const float sfin = shF * swo;

  const int lane = t & 63, warp = t >> 6;
  const int l15 = lane & 15, lq = lane >> 4;
  const int row0 = bid * 16;
  const unsigned char* brow = bits + (size_t)(row0 + l15) * 1024 + warp * 256;
  const _Float16* rrow = RT + (size_t)l15 * NN + warp * 2048 + lq * 8;
  f32x4 acc = {};
#pragma unroll 8
  for (int it = 0; it < 32; ++it) {
    uint2 w = *(const uint2*)(brow + it * 8);
#pragma unroll
    for (int kk = 0; kk < 2; ++kk) {
      half8 af = expand8(((kk ? w.y : w.x) >> (lq * 8)) & 0xffu);
      half8 bf = *(const half8*)(rrow + it * 64 + kk * 32);
      acc = __builtin_amdgcn_mfma_f32_16x16x32_f16(af, bf, acc, 0, 0, 0);
    }
  }
  if (warp > 0) {
#pragma unroll
    for (int i = 0; i < 4; ++i) red2s[warp - 1][lq * 4 + i][l15] = acc[i];
  }
  __syncthreads();
  if (warp == 0) {
#pragma unroll
    for (int i = 0; i < 4; ++i) {
      int r = lq * 4 + i;
      float v = acc[i] + red2s[0][r][l15] + red2s[1][r][l15] + red2s[2][r][l15];
      out[(size_t)(row0 + r) * DOUT + l15] = v * sfin;
    }
  }
}

extern "C" void kernel_launch(void* const* d_in, const int* in_sizes, int n_in,
                              void* d_out, int out_size, void* d_ws, size_t ws_size,
                              hipStream_t stream) {
  const float* A  = (const float*)d_in[0];
  const float* X  = (const float*)d_in[1];
  const float* Wi = (const float*)d_in[2];
  const float* Wo = (const float*)d_in[3];
  char* ws = (char*)d_ws;
  unsigned* part      = (unsigned*)(ws + OFF_PART);
  unsigned* part2     = (unsigned*)(ws + OFF_PART2);
  _Float16* Yb        = (_Float16*)(ws + OFF_YB);
  _Float16* RT        = (_Float16*)(ws + OFF_RT);
  float* hf           = (float*)(ws + OFF_HF);
  unsigned char* bits = (unsigned char*)(ws + OFF_BITS);
  float* P1           = (float*)(ws + OFF_P1);
  float* outp         = (float*)d_out;

  k_f0<<<512, 256, 0, stream>>>(A, X, Wi, Wo, bits, part);
  k_f1<<<512, 256, 0, stream>>>(X, Wi, part, Yb);
  k_f2<<<512, 256, 0, stream>>>(bits, Yb, P1);
  k_f3<<<512, 256, 0, stream>>>(P1, hf, part2);
  k_f4<<<512, 256, 0, stream>>>(hf, Wo, part, part2, RT);
  k_f5<<<512, 256, 0, stream>>>(bits, RT, part, part2, outp);
}

// Round 13
// 133.111 us; speedup vs baseline: 1.1806x; 1.1806x over previous
//
#include <hip/hip_runtime.h>

#define NN 8192
#define DIN 128
#define DH 64
#define DOUT 16

typedef _Float16 half8 __attribute__((ext_vector_type(8)));
typedef float f32x4 __attribute__((ext_vector_type(4)));

// workspace layout (bytes); ws ~1GB
#define OFF_PART  0u         // part[242]: 0..239 X partial max, 240 Wi, 241 Wo
#define OFF_PART2 2048u      // part2[128]: per-block max |h_int| (g1 writes all)
#define OFF_YB    65536u     // f16 [1024 kgrp][64 n][8 k7] (1 MB) Y ints |Y|<=384
#define OFF_RT    1114112u   // f16 [16][8192] (256 KB) R^T ints, k pi-permuted
#define OFF_HF    1376256u   // f32 [8192][64] (2 MB) h as RAW INTEGERS
#define OFF_BITS  3473408u   // u8  [8192][1024] (8 MB) A>0 bitmask, pi-permuted

// pi-permutation within each 256-element group (float4+ballot packing order):
// stored position p <-> element e = 4*(p&63) + (p>>6). Applied to bits, Yb, RT.
__device__ __forceinline__ int permk(int k) {
  int e = k & 255;
  return (k & ~255) | (((e & 3) << 6) | (e >> 2));
}

__device__ __forceinline__ float guard(float s) { return (s == 0.0f) ? 1.0f : s; }

__device__ __forceinline__ half8 expand8(unsigned bb) {  // 8 bits -> 8 f16 {0,1}
  uint4 w;
  w.x = ((bb & 1u)  ? 0x3C00u : 0u) | ((bb & 2u)   ? 0x3C000000u : 0u);
  w.y = ((bb & 4u)  ? 0x3C00u : 0u) | ((bb & 8u)   ? 0x3C000000u : 0u);
  w.z = ((bb & 16u) ? 0x3C00u : 0u) | ((bb & 32u)  ? 0x3C000000u : 0u);
  w.w = ((bb & 64u) ? 0x3C00u : 0u) | ((bb & 128u) ? 0x3C000000u : 0u);
  return __builtin_bit_cast(half8, w);
}

// K0 (R6-proven): blocks [0,4096): binarize A via ext-vec float4 + 4x ballot
// (coalesced, pi bit order free, NONTEMPORAL reads keep L2 clean).
// [4096,4338): abs-max partials.
__global__ __launch_bounds__(256) void k_f0(const float* __restrict__ A,
                                            const float* __restrict__ X,
                                            const float* __restrict__ Wi,
                                            const float* __restrict__ Wo,
                                            unsigned char* __restrict__ bits,
                                            unsigned* __restrict__ part) {
  const int t = threadIdx.x, bx = blockIdx.x;
  if (bx < 4096) {
    const int lane = t & 63, warp = t >> 6;
    const size_t wbase = ((size_t)bx * 4 + warp) * 4096;   // floats per wave
    const f32x4* ap = (const f32x4*)(A + wbase) + lane;
    unsigned char* bp = bits + (wbase >> 3);
#pragma unroll
    for (int g = 0; g < 16; ++g) {                         // 256 floats per group
      f32x4 v = __builtin_nontemporal_load(&ap[g * 64]);
      unsigned long long m0 = __ballot(v[0] > 0.0f);
      unsigned long long m1 = __ballot(v[1] > 0.0f);
      unsigned long long m2 = __ballot(v[2] > 0.0f);
      unsigned long long m3 = __ballot(v[3] > 0.0f);
      unsigned long long lo = (lane & 1) ? m1 : m0;
      unsigned long long hi = (lane & 1) ? m3 : m2;
      unsigned long long word = (lane & 2) ? hi : lo;
      if (lane < 4) *(unsigned long long*)(bp + g * 32 + lane * 8) = word;
    }
    return;
  }
  __shared__ float red[256];
  const int b = bx - 4096;
  float m = 0.0f;
  if (b < 240) {
    for (int i = b * 256 + t; i < NN * DIN; i += 240 * 256) m = fmaxf(m, fabsf(X[i]));
  } else if (b == 240) {
    for (int i = t; i < DIN * DH; i += 256) m = fmaxf(m, fabsf(Wi[i]));
  } else {
    for (int i = t; i < DH * DOUT; i += 256) m = fmaxf(m, fabsf(Wo[i]));
  }
  red[t] = m; __syncthreads();
  for (int s = 128; s > 0; s >>= 1) {
    if (t < s) red[t] = fmaxf(red[t], red[t + s]);
    __syncthreads();
  }
  if (t == 0) part[b] = __float_as_uint(red[0]);
}

// K1 (R6-proven): Yb[kp>>3][n][kp&7] = (Xq @ Wiq) exact ints; Wi quant inline.
__global__ __launch_bounds__(256) void k_f1(const float* __restrict__ X,
                                            const float* __restrict__ Wi,
                                            const unsigned* __restrict__ part,
                                            _Float16* __restrict__ Yb) {
  __shared__ float red[256];
  __shared__ float Xs[8][129];
  __shared__ float Ws[DIN][DH];
  const int t = threadIdx.x;
  red[t] = (t < 240) ? __uint_as_float(part[t]) : 0.0f;
  __syncthreads();
  for (int s = 128; s > 0; s >>= 1) {
    if (t < s) red[t] = fmaxf(red[t], red[t + s]);
    __syncthreads();
  }
  const float sx = guard(red[0] / 3.0f);                // qmax=3
  const float swi = guard(__uint_as_float(part[240]));  // qmax=1
  const int k0 = blockIdx.x * 8;
  __syncthreads();
  for (int i = t; i < 8 * DIN; i += 256) {
    int r = i >> 7, c = i & 127;
    float q = rintf(X[(size_t)(k0 + r) * DIN + c] / sx);
    Xs[r][c] = fminf(fmaxf(q, -3.0f), 3.0f);
  }
  for (int i = t; i < DIN * DH; i += 256) {
    float q = rintf(Wi[i] / swi);
    Ws[i >> 6][i & 63] = fminf(fmaxf(q, -1.0f), 1.0f);
  }
  __syncthreads();
  const int r = t & 7, jp = t >> 3, j = jp * 2;
  float a0 = 0.0f, a1 = 0.0f;
  for (int n = 0; n < DIN; ++n) {
    float xv = Xs[r][n];
    a0 = fmaf(xv, Ws[n][j], a0);
    a1 = fmaf(xv, Ws[n][j + 1], a1);
  }
  const int kp = permk(k0 + r);
  const size_t base = (size_t)(kp >> 3) * 512 + (size_t)j * 8 + (kp & 7);
  Yb[base]     = (_Float16)a0;   // exact integers in f16
  Yb[base + 8] = (_Float16)a1;
}

// K2: h_int = Aq @ Y, FULL K per block. BM=64, 128 blocks, 4 warps k-split 2048.
// No P1 round-trip: warp partials (exact ints) reduced via LDS; writes h_int raw
// + per-block max to part2. Yb read direct from L2 (128 blocks x 1MB = 128MB L2).
__global__ __launch_bounds__(256) void k_g1(const unsigned char* __restrict__ bits,
                                            const _Float16* __restrict__ Yb,
                                            float* __restrict__ hf,
                                            unsigned* __restrict__ part2) {
  __shared__ float hs[3][64][64];                // 48 KB
  const int t = threadIdx.x, lane = t & 63, warp = t >> 6;
  const int l15 = lane & 15, lq = lane >> 4;
  const int row0 = blockIdx.x * 64;
  f32x4 acc[4][4] = {};
  const unsigned char* b0 = bits + (size_t)(row0 + l15) * 1024 + warp * 256;
#pragma unroll 4
  for (int it = 0; it < 32; ++it) {
    uint2 w[4];
#pragma unroll
    for (int mt = 0; mt < 4; ++mt)
      w[mt] = *(const uint2*)(b0 + (size_t)mt * 16384 + it * 8);
#pragma unroll
    for (int kk = 0; kk < 2; ++kk) {
      const _Float16* yb = Yb + (size_t)(warp * 256 + it * 8 + kk * 4 + lq) * 512 + (size_t)l15 * 8;
      half8 bf[4];
#pragma unroll
      for (int nt = 0; nt < 4; ++nt) bf[nt] = *(const half8*)(yb + nt * 128);
#pragma unroll
      for (int mt = 0; mt < 4; ++mt) {
        half8 af = expand8(((kk ? w[mt].y : w[mt].x) >> (lq * 8)) & 0xffu);
#pragma unroll
        for (int nt = 0; nt < 4; ++nt)
          acc[mt][nt] = __builtin_amdgcn_mfma_f32_16x16x32_f16(af, bf[nt], acc[mt][nt], 0, 0, 0);
      }
    }
  }
  const int r4 = lq * 4;
  if (warp > 0) {
#pragma unroll
    for (int mt = 0; mt < 4; ++mt)
#pragma unroll
      for (int nt = 0; nt < 4; ++nt)
#pragma unroll
        for (int i = 0; i < 4; ++i)
          hs[warp - 1][mt * 16 + r4 + i][nt * 16 + l15] = acc[mt][nt][i];
  }
  __syncthreads();
  if (warp == 0) {
    float m = 0.0f;
#pragma unroll
    for (int mt = 0; mt < 4; ++mt) {
#pragma unroll
      for (int nt = 0; nt < 4; ++nt) {
#pragma unroll
        for (int i = 0; i < 4; ++i) {
          const int rr = mt * 16 + r4 + i, cc = nt * 16 + l15;
          float v = acc[mt][nt][i] + hs[0][rr][cc] + hs[1][rr][cc] + hs[2][rr][cc];
          hf[(size_t)(row0 + rr) * DH + cc] = v;      // raw exact integer
          m = fmaxf(m, fabsf(v));
        }
      }
    }
    for (int off = 32; off > 0; off >>= 1) m = fmaxf(m, __shfl_xor(m, off));
    if (t == 0) part2[blockIdx.x] = __float_as_uint(m);  // plain store
  }
}

// K3: R^T ints: hq = clip(round(h_int/(maxint/3))); Wo quant inline.
__global__ __launch_bounds__(256) void k_f4(const float* __restrict__ hf,
                                            const float* __restrict__ Wo,
                                            const unsigned* __restrict__ part,
                                            const unsigned* __restrict__ part2,
                                            _Float16* __restrict__ RT) {
  __shared__ float WoS[DH][DOUT];
  __shared__ float red4[256];
  const int t = threadIdx.x, bid = blockIdx.x;
  red4[t] = (t < 128) ? __uint_as_float(part2[t]) : 0.0f;
  __syncthreads();
  for (int s = 128; s > 0; s >>= 1) {
    if (t < s) red4[t] = fmaxf(red4[t], red4[t + s]);
    __syncthreads();
  }
  const float shi = guard(red4[0] / 3.0f);
  const float swo = guard(__uint_as_float(part[241]));
  for (int i = t; i < DH * DOUT; i += 256) {
    float q = rintf(Wo[i] / swo);
    WoS[i >> 4][i & 15] = fminf(fmaxf(q, -1.0f), 1.0f);
  }
  __syncthreads();
  const int i = bid * 16 + (t & 15), j = t >> 4;
  const float4* hp = (const float4*)(hf + (size_t)i * DH);
  float acc = 0.0f;
#pragma unroll 4
  for (int nb = 0; nb < 16; ++nb) {
    float4 h4 = hp[nb];
    float q;
    q = fminf(fmaxf(rintf(h4.x / shi), -3.0f), 3.0f); acc = fmaf(q, WoS[nb * 4 + 0][j], acc);
    q = fminf(fmaxf(rintf(h4.y / shi), -3.0f), 3.0f); acc = fmaf(q, WoS[nb * 4 + 1][j], acc);
    q = fminf(fmaxf(rintf(h4.z / shi), -3.0f), 3.0f); acc = fmaf(q, WoS[nb * 4 + 2][j], acc);
    q = fminf(fmaxf(rintf(h4.w / shi), -3.0f), 3.0f); acc = fmaf(q, WoS[nb * 4 + 3][j], acc);
  }
  RT[(size_t)j * NN + permk(i)] = (_Float16)acc;     // |R_int| <= 192, exact
}

// K4: out = (sx*swi)*(maxint/3)*swo * (Aq @ R_int), full K in-block (proven).
__global__ __launch_bounds__(256) void k_f5(const unsigned char* __restrict__ bits,
                                            const _Float16* __restrict__ RT,
                                            const unsigned* __restrict__ part,
                                            const unsigned* __restrict__ part2,
                                            float* __restrict__ out) {
  __shared__ float redP[256];
  __shared__ float red2s[3][16][16];
  const int t = threadIdx.x, bid = blockIdx.x;
  redP[t] = (t < 240) ? __uint_as_float(part[t]) : 0.0f;
  __syncthreads();
  for (int s = 128; s > 0; s >>= 1) {
    if (t < s) redP[t] = fmaxf(redP[t], redP[t + s]);
    __syncthreads();
  }
  const float sxraw = redP[0];
  __syncthreads();                                  // protect redP before reuse
  redP[t] = (t < 128) ? __uint_as_float(part2[t]) : 0.0f;
  __syncthreads();
  for (int s = 128; s > 0; s >>= 1) {
    if (t < s) redP[t] = fmaxf(redP[t], redP[t + s]);
    __syncthreads();
  }
  const float maxint = redP[0];
  const float swi = guard(__uint_as_float(part[240]));
  const float swo = guard(__uint_as_float(part[241]));
  const float sx = guard(sxraw / 3.0f);
  const float shF = (maxint == 0.0f) ? 1.0f : (sx * swi) * (maxint / 3.0f);
  const float sfin = shF * swo;

  const int lane = t & 63, warp = t >> 6;
  const int l15 = lane & 15, lq = lane >> 4;
  const int row0 = bid * 16;
  const unsigned char* brow = bits + (size_t)(row0 + l15) * 1024 + warp * 256;
  const _Float16* rrow = RT + (size_t)l15 * NN + warp * 2048 + lq * 8;
  f32x4 acc = {};
#pragma unroll 8
  for (int it = 0; it < 32; ++it) {
    uint2 w = *(const uint2*)(brow + it * 8);
#pragma unroll
    for (int kk = 0; kk < 2; ++kk) {
      half8 af = expand8(((kk ? w.y : w.x) >> (lq * 8)) & 0xffu);
      half8 bf = *(const half8*)(rrow + it * 64 + kk * 32);
      acc = __builtin_amdgcn_mfma_f32_16x16x32_f16(af, bf, acc, 0, 0, 0);
    }
  }
  if (warp > 0) {
#pragma unroll
    for (int i = 0; i < 4; ++i) red2s[warp - 1][lq * 4 + i][l15] = acc[i];
  }
  __syncthreads();
  if (warp == 0) {
#pragma unroll
    for (int i = 0; i < 4; ++i) {
      int r = lq * 4 + i;
      float v = acc[i] + red2s[0][r][l15] + red2s[1][r][l15] + red2s[2][r][l15];
      out[(size_t)(row0 + r) * DOUT + l15] = v * sfin;
    }
  }
}

extern "C" void kernel_launch(void* const* d_in, const int* in_sizes, int n_in,
                              void* d_out, int out_size, void* d_ws, size_t ws_size,
                              hipStream_t stream) {
  const float* A  = (const float*)d_in[0];
  const float* X  = (const float*)d_in[1];
  const float* Wi = (const float*)d_in[2];
  const float* Wo = (const float*)d_in[3];
  char* ws = (char*)d_ws;
  unsigned* part      = (unsigned*)(ws + OFF_PART);
  unsigned* part2     = (unsigned*)(ws + OFF_PART2);
  _Float16* Yb        = (_Float16*)(ws + OFF_YB);
  _Float16* RT        = (_Float16*)(ws + OFF_RT);
  float* hf           = (float*)(ws + OFF_HF);
  unsigned char* bits = (unsigned char*)(ws + OFF_BITS);
  float* outp         = (float*)d_out;

  k_f0<<<4338, 256, 0, stream>>>(A, X, Wi, Wo, bits, part);
  k_f1<<<1024, 256, 0, stream>>>(X, Wi, part, Yb);
  k_g1<<<128, 256, 0, stream>>>(bits, Yb, hf, part2);
  k_f4<<<512, 256, 0, stream>>>(hf, Wo, part, part2, RT);
  k_f5<<<512, 256, 0, stream>>>(bits, RT, part, part2, outp);
}